// Round 6
// baseline (1593.225 us; speedup 1.0000x reference)
//
#include <hip/hip_runtime.h>

typedef unsigned short u16;
typedef unsigned int   u32;
typedef unsigned long long u64;

typedef short bf16x8 __attribute__((ext_vector_type(8)));
typedef float f32x4  __attribute__((ext_vector_type(4)));

#define A_SYN  0.90483741803595957f   // exp(-0.5/5)
#define A_VM   0.95122942450071400f   // exp(-0.5/10)
#define BETA   0.04877057549928600f   // 1 - A_VM
#define C_RATE 0.09754115099857200f   // (1/DT)*(1-alpha_out) = 2*BETA
#define R_H    0.04419417382415922f   // 1*1*10/5 * sqrt(1/2048)
#define R_IN   4.41941738241592200f   // 10*1*10 * sqrt(1/512)
#define R_OUT  2.20970869120796080f   // 100 * sqrt(1/2048)

__device__ __forceinline__ u16 f2b(float f){
  u32 x = __float_as_uint(f);
  return (u16)((x + 0x7FFFu + ((x >> 16) & 1u)) >> 16);   // RNE f32->bf16
}
__device__ __forceinline__ float b2f(u16 u){ return __uint_as_float(((u32)u) << 16); }

// ---------------- prep: row sums of x -> sbeta[m]; convert x to bf16 ----------------
__global__ __launch_bounds__(256) void prep_x(const float* __restrict__ x,
                                              u16* __restrict__ xb,
                                              float* __restrict__ sbeta){
  const int m = blockIdx.x;
  const int tid = threadIdx.x;
  const float4 xv = ((const float4*)(x + (size_t)m * 1024))[tid];
  float s = xv.x + xv.y + xv.z + xv.w;
  #pragma unroll
  for (int off = 32; off > 0; off >>= 1) s += __shfl_down(s, off, 64);
  __shared__ float ps[4];
  if ((tid & 63) == 0) ps[tid >> 6] = s;
  __syncthreads();
  float tot = ps[0] + ps[1] + ps[2] + ps[3];
  float sc = fminf(30.0f / (tot + 1.0f), 10.0f) * (R_IN * BETA);
  if (tid == 0) sbeta[m] = sc;
  ushort4 o; o.x = f2b(xv.x); o.y = f2b(xv.y); o.z = f2b(xv.z); o.w = f2b(xv.w);
  ((ushort4*)(xb + (size_t)m * 1024))[tid] = o;
}

// ---------------- detect bool layout: int32 words (0/1) vs packed bytes ----------------
__global__ void detect_layout(const u32* __restrict__ khw, u32* __restrict__ flag){
  u32 bad = 0;
  #pragma unroll
  for (int i = 0; i < 4; ++i){ u32 v = khw[threadIdx.x + i * 256]; bad |= (v > 1u) ? 1u : 0u; }
  if (bad) *flag = 1u;
}

// ---------------- prep: kernel_in -> Bt[n][k] bf16 (transposed) ----------------
__global__ __launch_bounds__(256) void prep_bt(const int* __restrict__ ki,
                                               const u32* __restrict__ flag,
                                               u16* __restrict__ Bt){
  __shared__ u16 tile[64][65];
  const int k0 = blockIdx.x * 64, n0 = blockIdx.y * 64;
  const int tr = threadIdx.x >> 6, tc = threadIdx.x & 63;
  const bool bm = (*flag) != 0;
  const unsigned char* kib = (const unsigned char*)ki;
  #pragma unroll 4
  for (int r = 0; r < 16; ++r){
    int row = r * 4 + tr;
    size_t idx = (size_t)(k0 + row) * 4096 + (n0 + tc);
    int v = bm ? (int)kib[idx] : ki[idx];
    tile[row][tc] = v ? (u16)0x3F80 : (u16)0;
  }
  __syncthreads();
  #pragma unroll 4
  for (int r = 0; r < 16; ++r){
    int row = r * 4 + tr;
    Bt[(size_t)(n0 + row) * 1024 + (k0 + tc)] = tile[tc][row];
  }
}

// ---------------- prep: kernel_h -> khT bit-packed [w][n], bit j = kh[w*64+j][n] ----------------
__global__ __launch_bounds__(256) void prep_kh(const int* __restrict__ kh,
                                               const u32* __restrict__ flag,
                                               u64* __restrict__ khT){
  const int n = blockIdx.x * 256 + threadIdx.x;
  const int w = blockIdx.y;
  const bool bm = (*flag) != 0;
  const unsigned char* khb = (const unsigned char*)kh;
  u64 bits = 0;
  #pragma unroll 8
  for (int j = 0; j < 64; ++j){
    size_t idx = (size_t)(w * 64 + j) * 4096 + n;
    int v = bm ? (int)khb[idx] : kh[idx];
    bits |= (u64)(v & 1) << j;
  }
  khT[(size_t)w * 4096 + n] = bits;
}

// ---------------- prep: kernel_h -> khR bit-packed rows [p][w], bit l = kh[p][w*64+l] ----------------
__global__ __launch_bounds__(256) void prep_khR(const int* __restrict__ kh,
                                                const u32* __restrict__ flag,
                                                u64* __restrict__ khR){
  const int p = blockIdx.x * 4 + (threadIdx.x >> 6);
  const int e = threadIdx.x & 63;
  const bool bm = (*flag) != 0;
  u64 bits = 0;
  if (bm){
    const unsigned char* src = (const unsigned char*)kh + (size_t)p * 4096 + e * 64;
    #pragma unroll 8
    for (int l = 0; l < 64; ++l) bits |= (u64)(src[l] & 1) << l;
  } else {
    const int* src = kh + (size_t)p * 4096 + e * 64;
    #pragma unroll 8
    for (int l = 0; l < 64; ++l) bits |= (u64)(src[l] & 1) << l;
  }
  khR[(size_t)p * 64 + e] = bits;
}

// ---------------- bf16 GEMM with XCD swizzle ----------------
__global__ __launch_bounds__(256) void gemm_iin(const u16* __restrict__ A,
                                                const u16* __restrict__ Bm,
                                                const float* __restrict__ sbeta,
                                                u16* __restrict__ C){
  __shared__ u16 As[128 * 32];
  __shared__ u16 Bs[128 * 32];
  const int tid = threadIdx.x;
  const int lane = tid & 63, w = tid >> 6;
  const int wm = w >> 1, wn = w & 1;
  const int id = blockIdx.y * 128 + blockIdx.x;
  const int swz = (id & 7) * 512 + (id >> 3);
  const int m0 = (swz & 127) * 128, n0 = (swz >> 7) * 128;
  const int l15 = lane & 15, lq = lane >> 4;
  const int K = 1024;

  f32x4 acc[4][4];
  #pragma unroll
  for (int i = 0; i < 4; ++i)
    #pragma unroll
    for (int j = 0; j < 4; ++j) acc[i][j] = (f32x4){0.f, 0.f, 0.f, 0.f};

  const u16* ag = A  + (size_t)(m0 + (tid >> 2)) * K + (tid & 3) * 8;
  const u16* bg = Bm + (size_t)(n0 + (tid >> 2)) * K + (tid & 3) * 8;

  for (int kt = 0; kt < 32; ++kt){
    __builtin_amdgcn_global_load_lds((const __attribute__((address_space(1))) u32*)(ag + kt * 32),
        (__attribute__((address_space(3))) u32*)(As + tid * 8), 16, 0, 0);
    __builtin_amdgcn_global_load_lds((const __attribute__((address_space(1))) u32*)(ag + (size_t)64 * K + kt * 32),
        (__attribute__((address_space(3))) u32*)(As + 2048 + tid * 8), 16, 0, 0);
    __builtin_amdgcn_global_load_lds((const __attribute__((address_space(1))) u32*)(bg + kt * 32),
        (__attribute__((address_space(3))) u32*)(Bs + tid * 8), 16, 0, 0);
    __builtin_amdgcn_global_load_lds((const __attribute__((address_space(1))) u32*)(bg + (size_t)64 * K + kt * 32),
        (__attribute__((address_space(3))) u32*)(Bs + 2048 + tid * 8), 16, 0, 0);
    __syncthreads();
    bf16x8 af[4], bf[4];
    #pragma unroll
    for (int f = 0; f < 4; ++f){
      af[f] = *(const bf16x8*)(As + (wm * 64 + f * 16 + l15) * 32 + lq * 8);
      bf[f] = *(const bf16x8*)(Bs + (wn * 64 + f * 16 + l15) * 32 + lq * 8);
    }
    #pragma unroll
    for (int fm = 0; fm < 4; ++fm)
      #pragma unroll
      for (int fn = 0; fn < 4; ++fn)
        acc[fm][fn] = __builtin_amdgcn_mfma_f32_16x16x32_bf16(af[fm], bf[fn], acc[fm][fn], 0, 0, 0);
    __syncthreads();
  }

  float sb[4][4];
  #pragma unroll
  for (int fm = 0; fm < 4; ++fm)
    #pragma unroll
    for (int i = 0; i < 4; ++i)
      sb[fm][i] = sbeta[m0 + wm * 64 + fm * 16 + lq * 4 + i];
  #pragma unroll
  for (int fm = 0; fm < 4; ++fm)
    #pragma unroll
    for (int fn = 0; fn < 4; ++fn)
      #pragma unroll
      for (int i = 0; i < 4; ++i){
        size_t row = (size_t)(m0 + wm * 64 + fm * 16 + lq * 4 + i);
        int col = n0 + wn * 64 + fn * 16 + l15;
        C[row * 4096 + col] = f2b(acc[fm][fn][i] * sb[fm][i]);
      }
}

// ================= SNN scan: 512 threads, 8 neurons/thread, barrier-free seqlock =================
// flag byte per wave: (q&3)<<6 | cnt  (cnt: 0..4 events in seg; 0x3F = overflow -> masks)
// event u32: bits0-11 p | bit12 neg | bit13 hit | bits14-19 slot | bit20 install

struct ScanLds {
  u64 flag[2];                                   // one byte per wave, double-buffered
  u32 seg[2][8][4] __attribute__((aligned(16)));
  u64 fpos[2][64], fneg[2][64];                  // [j*8+w] (written only on overflow)
  u32 tag[64];                                   // hot-slot tags (install-only)
};

__device__ __forceinline__ void produce(
    int lane, int w, int buf, u32 par,
    const u64 (&bsp)[8], const u64 (&bfl)[8], bool wany, ScanLds* L)
{
  if (lane == 0){
    u32 cb = par << 6;
    if (wany){
      int cnt = 0;
      #pragma unroll
      for (int j = 0; j < 8; ++j) cnt += __popcll(bfl[j]);
      if (cnt <= 4){
        cb |= (u32)cnt;
        int idx = 0;
        #pragma unroll 1
        for (int j = 0; j < 8; ++j){
          u64 m = bfl[j];
          while (m){
            int bit = (int)__builtin_ctzll(m); m &= m - 1;
            u32 p = (u32)(j * 512 + w * 64 + bit);
            u32 rising = (u32)((bsp[j] >> bit) & 1ull);
            u32 neg = (j < 4) ? (rising ^ 1u) : rising;   // dale sign (exc iff p<2048)
            u32 s = (p ^ (p >> 6)) & 63u;
            u32 tg = L->tag[s];
            u32 ev = p | (neg << 12) | (s << 14);
            if (tg == p) ev |= (1u << 13);                // hit
            else if (tg == 0xFFFFFFFFu) ev |= (1u << 20); // miss -> install
            L->seg[buf][w][idx++] = ev;
          }
        }
      } else {
        cb |= 0x3Fu;
        #pragma unroll
        for (int j = 0; j < 8; ++j){
          L->fpos[buf][j * 8 + w] = bfl[j] & bsp[j];
          L->fneg[buf][j * 8 + w] = bfl[j] & ~bsp[j];
        }
      }
      asm volatile("s_waitcnt lgkmcnt(0)" ::: "memory");  // data before flag
    }
    ((volatile unsigned char*)&L->flag[buf])[w] = (unsigned char)cb;
  }
}

__device__ __forceinline__ void apply_ev(
    u32 ev, int tid, int lane, int w,
    const u64* __restrict__ khR,
    ScanLds* L, int (&acc)[8], u64 (&hotbits)[8])
{
  u32 p = ev & 4095u;
  u32 s = (ev >> 14) & 63u;
  int sg = (ev & (1u << 12)) ? -1 : 1;
  if (ev & (1u << 13)){                       // hit: pure VALU
    #pragma unroll
    for (int j = 0; j < 8; ++j)
      acc[j] += sg * (int)((hotbits[j] >> s) & 1ull);
  } else {
    const u64* rp = khR + ((size_t)p << 6) + w;
    if (ev & (1u << 20)){                     // miss + install
      u64 sm = 1ull << s;
      #pragma unroll
      for (int j = 0; j < 8; ++j){
        u64 r = rp[8 * j];
        u64 bit = (r >> lane) & 1ull;
        acc[j] += sg * (int)bit;
        hotbits[j] = (hotbits[j] & ~sm) | (bit << s);
      }
      if (tid == 0) L->tag[s] = p;
    } else {                                  // miss (collision): no install
      #pragma unroll
      for (int j = 0; j < 8; ++j)
        acc[j] += sg * (int)((rp[8 * j] >> lane) & 1ull);
    }
  }
}

__device__ __forceinline__ void consume(
    int tid, int lane, int w, int buf, u32 par,
    const u64* __restrict__ khT, const u64* __restrict__ khR,
    ScanLds* L, int (&acc)[8], float (&racc)[8], u64 (&hotbits)[8])
{
  const volatile u32* fp = (const volatile u32*)&L->flag[buf];
  const u64 rep = 0x4040404040404040ull * (u64)par;
  u64 cw;
  for (;;){
    u32 lo = fp[0], hi = fp[1];
    cw = ((u64)hi << 32) | lo;
    if (((cw ^ rep) & 0xC0C0C0C0C0C0C0C0ull) == 0ull) break;
  }
  asm volatile("" ::: "memory");              // fence: seg/mask reads stay below poll
  if ((cw & 0x3F3F3F3F3F3F3F3Full) == 0ull) return;
  #pragma unroll 1
  for (int ww = 0; ww < 8; ++ww){
    u32 c = (u32)((cw >> (8 * ww)) & 0x3Full);
    if (!c) continue;
    if (c == 0x3Fu){
      // dense: this wave overflowed -> khT popcount over its 8 presyn words
      #pragma unroll 1
      for (int j = 0; j < 8; ++j){
        int w2 = j * 8 + ww;
        u64 fpm = L->fpos[buf][w2], fnm = L->fneg[buf][w2];
        if (!(fpm | fnm)) continue;
        const u64* kp = khT + ((size_t)w2 << 12) + tid;
        #pragma unroll
        for (int jj = 0; jj < 8; ++jj){
          u64 k = kp[512 * jj];
          int tt = __popcll(fpm & k) - __popcll(fnm & k);
          acc[jj] += (w2 < 32) ? tt : -tt;
        }
      }
    } else {
      uint4 q = *(const uint4*)&L->seg[buf][ww][0];
      u32 evs[4] = {q.x, q.y, q.z, q.w};
      #pragma unroll
      for (int i = 0; i < 4; ++i)
        if ((u32)i < c) apply_ev(evs[i], tid, lane, w, khR, L, acc, hotbits);
    }
  }
  #pragma unroll
  for (int j = 0; j < 8; ++j) racc[j] = R_H * (float)acc[j];
}

__device__ __forceinline__ void snn_step(
    int t, int tid, int lane, int w, const u16* __restrict__ ip,
    const u64* __restrict__ khT, const u64* __restrict__ khR,
    u16 (&cur)[8],
    float (&v)[8], float (&isy)[8], float (&rate)[8], float (&rsum)[8],
    float (&racc)[8], int (&acc)[8], u32 &prevm, u64 (&hotbits)[8],
    ScanLds* L)
{
  const int q = t + 1, buf = q & 1;
  const u32 par = (u32)(q & 3);
  u32 snm = 0;
  #pragma unroll
  for (int j = 0; j < 8; ++j){
    isy[j] = fmaf(isy[j], A_SYN, racc[j]);
    float tv = fmaf(isy[j], BETA, b2f(cur[j]));   // beta*i_syn + beta*R_in*scale*(x@Kin)
    float vv = fmaf(v[j], A_VM, tv);
    bool sj = vv > 1.0f;
    v[j] = sj ? 0.0f : vv;
    rate[j] = fmaf(rate[j], A_VM, sj ? C_RATE : 0.0f);  // alpha_out == alpha_vm
    rsum[j] += rate[j];
    snm |= (u32)sj << j;
  }
  const u32 flm = snm ^ prevm;
  prevm = snm;
  // refill cur for t+4 (4 steps of slack, no barrier drain anywhere)
  if (t + 4 < 256){
    const u16* qp = ip + (size_t)(t + 4) * 4096;
    #pragma unroll
    for (int j = 0; j < 8; ++j) cur[j] = qp[j * 512];
  }
  const bool wany = __any(flm != 0);     // steady state: single ballot
  u64 bsp[8], bfl[8];
  if (wany){
    #pragma unroll
    for (int j = 0; j < 8; ++j){
      bsp[j] = __ballot((int)((snm >> j) & 1u));
      bfl[j] = __ballot((int)((flm >> j) & 1u));
    }
  } else {
    #pragma unroll
    for (int j = 0; j < 8; ++j){ bsp[j] = 0; bfl[j] = 0; }
  }
  produce(lane, w, buf, par, bsp, bfl, wany, L);
  consume(tid, lane, w, buf, par, khT, khR, L, acc, racc, hotbits);
}

__global__ __launch_bounds__(512, 1) void snn_scan(
    const u16* __restrict__ iin, const u64* __restrict__ khT,
    const u64* __restrict__ khR,
    const float* __restrict__ v0, const float* __restrict__ is0,
    const float* __restrict__ r0, const int* __restrict__ s0,
    float* __restrict__ dout, float* __restrict__ rmean)
{
  const int b = blockIdx.x, tid = threadIdx.x;
  const int lane = tid & 63, w = tid >> 6;     // 8 waves
  __shared__ ScanLds L;

  if (tid < 64) L.tag[tid] = 0xFFFFFFFFu;
  if (tid == 0){ L.flag[0] = ~0ull; L.flag[1] = ~0ull; }  // par bits = 3: no false match

  float v[8], isy[8], rate[8], rsum[8], racc[8];
  int acc[8]; u64 hotbits[8]; u32 prevm = 0;
  const size_t base = (size_t)b * 4096 + tid;
  const unsigned char* s0b = (const unsigned char*)s0;   // spike0 all-zero; byte-safe either layout
  #pragma unroll
  for (int j = 0; j < 8; ++j){
    v[j]    = v0 [base + j * 512];
    isy[j]  = is0[base + j * 512];
    rate[j] = r0 [base + j * 512];
    rsum[j] = 0.f;
    prevm |= (u32)(s0b[base + j * 512] != 0) << j;
    acc[j] = 0; racc[j] = 0.f; hotbits[j] = 0ull;
  }
  __syncthreads();   // one-time: tag/flag init visible to all waves

  { // init event (q=0, buf=0, par=0): flips = spike0 rising
    u64 bsp[8], bfl[8];
    #pragma unroll
    for (int j = 0; j < 8; ++j){
      bsp[j] = __ballot((int)((prevm >> j) & 1u));
      bfl[j] = bsp[j];
    }
    bool wany = __any(prevm != 0);
    produce(lane, w, 0, 0, bsp, bfl, wany, &L);
    consume(tid, lane, w, 0, 0, khT, khR, &L, acc, racc, hotbits);
  }

  const u16* ip = iin + (size_t)b * 256 * 4096 + tid;
  u16 bufA[8], bufB[8], bufC[8], bufD[8];
  #pragma unroll
  for (int j = 0; j < 8; ++j) bufA[j] = ip[j * 512];
  #pragma unroll
  for (int j = 0; j < 8; ++j) bufB[j] = ip[4096 + j * 512];
  #pragma unroll
  for (int j = 0; j < 8; ++j) bufC[j] = ip[8192 + j * 512];
  #pragma unroll
  for (int j = 0; j < 8; ++j) bufD[j] = ip[12288 + j * 512];

  for (int t = 0; t < 256; t += 4){
    snn_step(t,     tid, lane, w, ip, khT, khR, bufA,
             v, isy, rate, rsum, racc, acc, prevm, hotbits, &L);
    snn_step(t + 1, tid, lane, w, ip, khT, khR, bufB,
             v, isy, rate, rsum, racc, acc, prevm, hotbits, &L);
    snn_step(t + 2, tid, lane, w, ip, khT, khR, bufC,
             v, isy, rate, rsum, racc, acc, prevm, hotbits, &L);
    snn_step(t + 3, tid, lane, w, ip, khT, khR, bufD,
             v, isy, rate, rsum, racc, acc, prevm, hotbits, &L);
  }

  #pragma unroll
  for (int j = 0; j < 8; ++j){
    size_t o = base + (size_t)j * 512;
    dout[o]           = v[j];
    dout[262144 + o]  = isy[j];
    dout[524288 + o]  = rate[j];
    dout[786432 + o]  = ((prevm >> j) & 1u) ? 1.0f : 0.0f;
    rmean[o] = rsum[j] * 0.00390625f;
  }
}

// ---------------- output head: R_out * rate_mean @ (kernel_out & exc_mask) ----------------
__global__ __launch_bounds__(256) void out_gemm(const float* __restrict__ rmean,
                                                const int* __restrict__ ko,
                                                const u32* __restrict__ flag,
                                                float* __restrict__ dout){
  const int b = blockIdx.x;
  const int o = blockIdx.y * 256 + threadIdx.x;
  const bool bm = (*flag) != 0;
  const unsigned char* kob = (const unsigned char*)ko;
  const float* rm = rmean + (size_t)b * 4096;
  float s = 0.f;
  #pragma unroll 8
  for (int n = 0; n < 2048; ++n){
    size_t idx = (size_t)n * 512 + o;
    int kv = bm ? (int)kob[idx] : ko[idx];
    s += rm[n] * (float)kv;
  }
  dout[1048576 + (size_t)b * 512 + o] = R_OUT * s;
}

extern "C" void kernel_launch(void* const* d_in, const int* in_sizes, int n_in,
                              void* d_out, int out_size, void* d_ws, size_t ws_size,
                              hipStream_t stream){
  (void)in_sizes; (void)n_in; (void)out_size; (void)ws_size;
  const float* x   = (const float*)d_in[0];
  const float* v0  = (const float*)d_in[1];
  const float* is0 = (const float*)d_in[2];
  const float* r0  = (const float*)d_in[3];
  const int*   s0  = (const int*)d_in[4];
  const int*   kin = (const int*)d_in[5];
  const int*   kh  = (const int*)d_in[6];
  const int*   ko  = (const int*)d_in[7];
  float* out = (float*)d_out;
  char* ws = (char*)d_ws;

  // rmean overlaps xb: xb is dead after gemm_iin, rmean written by snn_scan afterwards.
  u16*  xb    = (u16*)(ws);                       // [0, 33554432)
  float* rmean= (float*)(ws);                     // [0, 1048576)  lifetime-disjoint with xb
  float* sbeta= (float*)(ws + 33554432);          // 65,536 B
  u16*  iin   = (u16*)(ws + 33619968);            // 134,217,728 B
  u16*  Bt    = (u16*)(ws + 167837696);           // 8,388,608 B
  u64*  khT   = (u64*)(ws + 176226304);           // 2,097,152 B
  u64*  khR   = (u64*)(ws + 178323456);           // 2,097,152 B
  u32*  flag  = (u32*)(ws + 180420608);           // 4 B

  hipMemsetAsync(flag, 0, 4, stream);
  detect_layout<<<dim3(1), dim3(256), 0, stream>>>((const u32*)kh, flag);
  prep_x<<<dim3(16384), dim3(256), 0, stream>>>(x, xb, sbeta);
  prep_bt<<<dim3(16, 64), dim3(256), 0, stream>>>(kin, flag, Bt);
  prep_kh<<<dim3(16, 64), dim3(256), 0, stream>>>(kh, flag, khT);
  prep_khR<<<dim3(1024), dim3(256), 0, stream>>>(kh, flag, khR);
  gemm_iin<<<dim3(128, 32), dim3(256), 0, stream>>>(xb, Bt, sbeta, iin);
  snn_scan<<<dim3(64), dim3(512), 0, stream>>>(iin, khT, khR, v0, is0, r0, s0, out, rmean);
  out_gemm<<<dim3(64, 2), dim3(256), 0, stream>>>(rmean, ko, flag, out);
}

// Round 7
// 1564.273 us; speedup vs baseline: 1.0185x; 1.0185x over previous
//
#include <hip/hip_runtime.h>

typedef unsigned short u16;
typedef unsigned int   u32;
typedef unsigned long long u64;

typedef short bf16x8 __attribute__((ext_vector_type(8)));
typedef float f32x4  __attribute__((ext_vector_type(4)));

#define A_SYN  0.90483741803595957f   // exp(-0.5/5)
#define A_VM   0.95122942450071400f   // exp(-0.5/10)
#define BETA   0.04877057549928600f   // 1 - A_VM
#define C_RATE 0.09754115099857200f   // (1/DT)*(1-alpha_out) = 2*BETA
#define R_H    0.04419417382415922f   // 1*1*10/5 * sqrt(1/2048)
#define R_IN   4.41941738241592200f   // 10*1*10 * sqrt(1/512)
#define R_OUT  2.20970869120796080f   // 100 * sqrt(1/2048)

__device__ __forceinline__ u16 f2b(float f){
  u32 x = __float_as_uint(f);
  return (u16)((x + 0x7FFFu + ((x >> 16) & 1u)) >> 16);   // RNE f32->bf16
}
__device__ __forceinline__ float b2f(u16 u){ return __uint_as_float(((u32)u) << 16); }

// ---------------- prep: row sums of x -> sbeta[m]; convert x to bf16 ----------------
__global__ __launch_bounds__(256) void prep_x(const float* __restrict__ x,
                                              u16* __restrict__ xb,
                                              float* __restrict__ sbeta){
  const int m = blockIdx.x;
  const int tid = threadIdx.x;
  const float4 xv = ((const float4*)(x + (size_t)m * 1024))[tid];
  float s = xv.x + xv.y + xv.z + xv.w;
  #pragma unroll
  for (int off = 32; off > 0; off >>= 1) s += __shfl_down(s, off, 64);
  __shared__ float ps[4];
  if ((tid & 63) == 0) ps[tid >> 6] = s;
  __syncthreads();
  float tot = ps[0] + ps[1] + ps[2] + ps[3];
  float sc = fminf(30.0f / (tot + 1.0f), 10.0f) * (R_IN * BETA);
  if (tid == 0) sbeta[m] = sc;
  ushort4 o; o.x = f2b(xv.x); o.y = f2b(xv.y); o.z = f2b(xv.z); o.w = f2b(xv.w);
  ((ushort4*)(xb + (size_t)m * 1024))[tid] = o;
}

// ---------------- detect bool layout: int32 words (0/1) vs packed bytes ----------------
__global__ void detect_layout(const u32* __restrict__ khw, u32* __restrict__ flag){
  u32 bad = 0;
  #pragma unroll
  for (int i = 0; i < 4; ++i){ u32 v = khw[threadIdx.x + i * 256]; bad |= (v > 1u) ? 1u : 0u; }
  if (bad) *flag = 1u;
}

// ---------------- prep: kernel_in -> Bt[n][k] bf16 (transposed) ----------------
__global__ __launch_bounds__(256) void prep_bt(const int* __restrict__ ki,
                                               const u32* __restrict__ flag,
                                               u16* __restrict__ Bt){
  __shared__ u16 tile[64][65];
  const int k0 = blockIdx.x * 64, n0 = blockIdx.y * 64;
  const int tr = threadIdx.x >> 6, tc = threadIdx.x & 63;
  const bool bm = (*flag) != 0;
  const unsigned char* kib = (const unsigned char*)ki;
  #pragma unroll 4
  for (int r = 0; r < 16; ++r){
    int row = r * 4 + tr;
    size_t idx = (size_t)(k0 + row) * 4096 + (n0 + tc);
    int v = bm ? (int)kib[idx] : ki[idx];
    tile[row][tc] = v ? (u16)0x3F80 : (u16)0;
  }
  __syncthreads();
  #pragma unroll 4
  for (int r = 0; r < 16; ++r){
    int row = r * 4 + tr;
    Bt[(size_t)(n0 + row) * 1024 + (k0 + tc)] = tile[tc][row];
  }
}

// ---------------- prep: kernel_h -> khT bit-packed [w][n], bit j = kh[w*64+j][n] ----------------
__global__ __launch_bounds__(256) void prep_kh(const int* __restrict__ kh,
                                               const u32* __restrict__ flag,
                                               u64* __restrict__ khT){
  const int n = blockIdx.x * 256 + threadIdx.x;
  const int w = blockIdx.y;
  const bool bm = (*flag) != 0;
  const unsigned char* khb = (const unsigned char*)kh;
  u64 bits = 0;
  #pragma unroll 8
  for (int j = 0; j < 64; ++j){
    size_t idx = (size_t)(w * 64 + j) * 4096 + n;
    int v = bm ? (int)khb[idx] : kh[idx];
    bits |= (u64)(v & 1) << j;
  }
  khT[(size_t)w * 4096 + n] = bits;
}

// ---------------- prep: kernel_h -> khB bytes: khB[p][c] bit j = kh[p][j*512+c] ----------------
__global__ __launch_bounds__(256) void prep_khB(const int* __restrict__ kh,
                                                const u32* __restrict__ flag,
                                                unsigned char* __restrict__ khB){
  const int p = blockIdx.x;
  const bool bm = (*flag) != 0;
  #pragma unroll
  for (int half = 0; half < 2; ++half){
    const int c = threadIdx.x + half * 256;
    u32 b = 0;
    if (bm){
      const unsigned char* r = (const unsigned char*)kh + (size_t)p * 4096;
      #pragma unroll
      for (int j = 0; j < 8; ++j) b |= (u32)(r[j * 512 + c] & 1) << j;
    } else {
      const int* r = kh + (size_t)p * 4096;
      #pragma unroll
      for (int j = 0; j < 8; ++j) b |= (u32)(r[j * 512 + c] & 1) << j;
    }
    khB[((size_t)p << 9) + c] = (unsigned char)b;
  }
}

// ---------------- bf16 GEMM with XCD swizzle ----------------
__global__ __launch_bounds__(256) void gemm_iin(const u16* __restrict__ A,
                                                const u16* __restrict__ Bm,
                                                const float* __restrict__ sbeta,
                                                u16* __restrict__ C){
  __shared__ u16 As[128 * 32];
  __shared__ u16 Bs[128 * 32];
  const int tid = threadIdx.x;
  const int lane = tid & 63, w = tid >> 6;
  const int wm = w >> 1, wn = w & 1;
  const int id = blockIdx.y * 128 + blockIdx.x;
  const int swz = (id & 7) * 512 + (id >> 3);
  const int m0 = (swz & 127) * 128, n0 = (swz >> 7) * 128;
  const int l15 = lane & 15, lq = lane >> 4;
  const int K = 1024;

  f32x4 acc[4][4];
  #pragma unroll
  for (int i = 0; i < 4; ++i)
    #pragma unroll
    for (int j = 0; j < 4; ++j) acc[i][j] = (f32x4){0.f, 0.f, 0.f, 0.f};

  const u16* ag = A  + (size_t)(m0 + (tid >> 2)) * K + (tid & 3) * 8;
  const u16* bg = Bm + (size_t)(n0 + (tid >> 2)) * K + (tid & 3) * 8;

  for (int kt = 0; kt < 32; ++kt){
    __builtin_amdgcn_global_load_lds((const __attribute__((address_space(1))) u32*)(ag + kt * 32),
        (__attribute__((address_space(3))) u32*)(As + tid * 8), 16, 0, 0);
    __builtin_amdgcn_global_load_lds((const __attribute__((address_space(1))) u32*)(ag + (size_t)64 * K + kt * 32),
        (__attribute__((address_space(3))) u32*)(As + 2048 + tid * 8), 16, 0, 0);
    __builtin_amdgcn_global_load_lds((const __attribute__((address_space(1))) u32*)(bg + kt * 32),
        (__attribute__((address_space(3))) u32*)(Bs + tid * 8), 16, 0, 0);
    __builtin_amdgcn_global_load_lds((const __attribute__((address_space(1))) u32*)(bg + (size_t)64 * K + kt * 32),
        (__attribute__((address_space(3))) u32*)(Bs + 2048 + tid * 8), 16, 0, 0);
    __syncthreads();
    bf16x8 af[4], bf[4];
    #pragma unroll
    for (int f = 0; f < 4; ++f){
      af[f] = *(const bf16x8*)(As + (wm * 64 + f * 16 + l15) * 32 + lq * 8);
      bf[f] = *(const bf16x8*)(Bs + (wn * 64 + f * 16 + l15) * 32 + lq * 8);
    }
    #pragma unroll
    for (int fm = 0; fm < 4; ++fm)
      #pragma unroll
      for (int fn = 0; fn < 4; ++fn)
        acc[fm][fn] = __builtin_amdgcn_mfma_f32_16x16x32_bf16(af[fm], bf[fn], acc[fm][fn], 0, 0, 0);
    __syncthreads();
  }

  float sb[4][4];
  #pragma unroll
  for (int fm = 0; fm < 4; ++fm)
    #pragma unroll
    for (int i = 0; i < 4; ++i)
      sb[fm][i] = sbeta[m0 + wm * 64 + fm * 16 + lq * 4 + i];
  #pragma unroll
  for (int fm = 0; fm < 4; ++fm)
    #pragma unroll
    for (int fn = 0; fn < 4; ++fn)
      #pragma unroll
      for (int i = 0; i < 4; ++i){
        size_t row = (size_t)(m0 + wm * 64 + fm * 16 + lq * 4 + i);
        int col = n0 + wn * 64 + fn * 16 + l15;
        C[row * 4096 + col] = f2b(acc[fm][fn][i] * sb[fm][i]);
      }
}

// ================= SNN scan: 512 threads, 8 neurons/thread (n = tid + 512j) =================
// Barrier protocol (r5, fastest). Events raw (p | neg<<12), per-wave segs of <=4.
// Consume: gather all events -> issue ALL khB byte loads upfront -> pure-VALU apply.

struct ScanLds {
  unsigned char cntb[2][8];                      // per-wave flip count (0xFF = dense)
  u32 seg[2][8][4] __attribute__((aligned(16)));
  u64 fpos[2][64], fneg[2][64];                  // [j*8+w], dense path only
};

__device__ __forceinline__ void produce(
    int lane, int w, int buf,
    const u64 (&bsp)[8], const u64 (&bfl)[8], bool wany, ScanLds* L)
{
  if (lane == 0){
    u32 cb = 0;
    if (wany){
      int cnt = 0;
      #pragma unroll
      for (int j = 0; j < 8; ++j) cnt += __popcll(bfl[j]);
      if (cnt <= 4){
        cb = (u32)cnt;
        int idx = 0;
        #pragma unroll 1
        for (int j = 0; j < 8; ++j){
          u64 m = bfl[j];
          while (m){
            int bit = (int)__builtin_ctzll(m); m &= m - 1;
            u32 p = (u32)(j * 512 + w * 64 + bit);
            u32 rising = (u32)((bsp[j] >> bit) & 1ull);
            u32 neg = (j < 4) ? (rising ^ 1u) : rising;   // dale sign (exc iff p<2048)
            L->seg[buf][w][idx++] = p | (neg << 12);
          }
        }
      } else {
        cb = 0xFFu;
        #pragma unroll
        for (int j = 0; j < 8; ++j){
          L->fpos[buf][j * 8 + w] = bfl[j] & bsp[j];
          L->fneg[buf][j * 8 + w] = bfl[j] & ~bsp[j];
        }
      }
    }
    L->cntb[buf][w] = (unsigned char)cb;
  }
}

__device__ __forceinline__ void consume(
    int tid, int buf,
    const u64* __restrict__ khT, const unsigned char* __restrict__ khB,
    ScanLds* L, int (&acc)[8], float (&racc)[8])
{
  const u64 cw = *(const u64*)&L->cntb[buf][0];
  if (cw == 0ull) return;

  u32 evs[8][4], byv[8][4];
  // phase 1: read segs, issue ALL khB byte loads (independent -> one latency)
  #pragma unroll
  for (int ww = 0; ww < 8; ++ww){
    u32 c = (u32)((cw >> (8 * ww)) & 0xFFull);
    if (c == 0u || c == 0xFFu) continue;          // wave-uniform branch
    uint4 q = *(const uint4*)&L->seg[buf][ww][0];
    evs[ww][0] = q.x; evs[ww][1] = q.y; evs[ww][2] = q.z; evs[ww][3] = q.w;
    #pragma unroll
    for (int k = 0; k < 4; ++k)
      if ((u32)k < c)
        byv[ww][k] = khB[((size_t)(evs[ww][k] & 4095u) << 9) + tid];
  }
  // phase 2: dense waves (t=0 onset / ultra-rare bursts)
  if (cw & 0x8080808080808080ull){
    #pragma unroll 1
    for (int ww = 0; ww < 8; ++ww){
      if (((cw >> (8 * ww)) & 0xFFull) != 0xFFull) continue;
      #pragma unroll 1
      for (int j = 0; j < 8; ++j){
        int w2 = j * 8 + ww;
        u64 fpm = L->fpos[buf][w2], fnm = L->fneg[buf][w2];
        if (!(fpm | fnm)) continue;
        const u64* kp = khT + ((size_t)w2 << 12) + tid;
        #pragma unroll
        for (int jj = 0; jj < 8; ++jj){
          u64 k = kp[512 * jj];
          int tt = __popcll(fpm & k) - __popcll(fnm & k);
          acc[jj] += (w2 < 32) ? tt : -tt;
        }
      }
    }
  }
  // phase 3: apply sparse events (pure VALU)
  #pragma unroll
  for (int ww = 0; ww < 8; ++ww){
    u32 c = (u32)((cw >> (8 * ww)) & 0xFFull);
    if (c == 0u || c == 0xFFu) continue;
    #pragma unroll
    for (int k = 0; k < 4; ++k){
      if ((u32)k < c){
        u32 b = byv[ww][k];
        if (evs[ww][k] & (1u << 12)){
          #pragma unroll
          for (int j = 0; j < 8; ++j) acc[j] -= (int)((b >> j) & 1u);
        } else {
          #pragma unroll
          for (int j = 0; j < 8; ++j) acc[j] += (int)((b >> j) & 1u);
        }
      }
    }
  }
  #pragma unroll
  for (int j = 0; j < 8; ++j) racc[j] = R_H * (float)acc[j];
}

__device__ __forceinline__ void snn_step(
    int t, int tid, int lane, int w, const u16* __restrict__ ip,
    const u64* __restrict__ khT, const unsigned char* __restrict__ khB,
    u16 (&cur)[8],
    float (&v)[8], float (&isy)[8], float (&rate)[8], float (&rsum)[8],
    float (&racc)[8], int (&acc)[8], u32 &prevm,
    ScanLds* L)
{
  const int buf = t & 1;
  u32 snm = 0;
  #pragma unroll
  for (int j = 0; j < 8; ++j){
    isy[j] = fmaf(isy[j], A_SYN, racc[j]);
    float tv = fmaf(isy[j], BETA, b2f(cur[j]));   // beta*i_syn + beta*R_in*scale*(x@Kin)
    float vv = fmaf(v[j], A_VM, tv);
    bool sj = vv > 1.0f;
    v[j] = sj ? 0.0f : vv;
    rate[j] = fmaf(rate[j], A_VM, sj ? C_RATE : 0.0f);  // alpha_out == alpha_vm
    rsum[j] += rate[j];
    snm |= (u32)sj << j;
  }
  const u32 flm = snm ^ prevm;
  prevm = snm;
  const bool wany = __any(flm != 0);     // steady state: one ballot
  u64 bsp[8], bfl[8];
  if (wany){
    #pragma unroll
    for (int j = 0; j < 8; ++j){
      bsp[j] = __ballot((int)((snm >> j) & 1u));
      bfl[j] = __ballot((int)((flm >> j) & 1u));
    }
  }
  produce(lane, w, buf, bsp, bfl, wany, L);
  __syncthreads();
  // refill cur for t+2 AFTER the barrier: drains at the NEXT barrier (full step of slack)
  if (t + 2 < 256){
    const u16* qp = ip + (size_t)(t + 2) * 4096;
    #pragma unroll
    for (int j = 0; j < 8; ++j) cur[j] = qp[j * 512];
  }
  consume(tid, buf, khT, khB, L, acc, racc);
}

__global__ __launch_bounds__(512, 2) void snn_scan(
    const u16* __restrict__ iin, const u64* __restrict__ khT,
    const unsigned char* __restrict__ khB,
    const float* __restrict__ v0, const float* __restrict__ is0,
    const float* __restrict__ r0, const int* __restrict__ s0,
    float* __restrict__ dout, float* __restrict__ rmean)
{
  const int b = blockIdx.x, tid = threadIdx.x;
  const int lane = tid & 63, w = tid >> 6;     // 8 waves
  __shared__ ScanLds L;

  float v[8], isy[8], rate[8], rsum[8], racc[8];
  int acc[8]; u32 prevm = 0;
  const size_t base = (size_t)b * 4096 + tid;
  const unsigned char* s0b = (const unsigned char*)s0;   // spike0 all-zero; byte-safe either layout
  #pragma unroll
  for (int j = 0; j < 8; ++j){
    v[j]    = v0 [base + j * 512];
    isy[j]  = is0[base + j * 512];
    rate[j] = r0 [base + j * 512];
    rsum[j] = 0.f;
    prevm |= (u32)(s0b[base + j * 512] != 0) << j;
    acc[j] = 0; racc[j] = 0.f;
  }

  { // init event (buf=1): flips = spike0 rising
    u64 bsp[8], bfl[8];
    bool wany = __any(prevm != 0);
    if (wany){
      #pragma unroll
      for (int j = 0; j < 8; ++j){
        bsp[j] = __ballot((int)((prevm >> j) & 1u));
        bfl[j] = bsp[j];
      }
    }
    produce(lane, w, 1, bsp, bfl, wany, &L);
    __syncthreads();
    consume(tid, 1, khT, khB, &L, acc, racc);
  }

  const u16* ip = iin + (size_t)b * 256 * 4096 + tid;
  u16 bufA[8], bufB[8];
  #pragma unroll
  for (int j = 0; j < 8; ++j) bufA[j] = ip[j * 512];
  #pragma unroll
  for (int j = 0; j < 8; ++j) bufB[j] = ip[4096 + j * 512];

  for (int t = 0; t < 256; t += 2){
    snn_step(t,     tid, lane, w, ip, khT, khB, bufA,
             v, isy, rate, rsum, racc, acc, prevm, &L);
    snn_step(t + 1, tid, lane, w, ip, khT, khB, bufB,
             v, isy, rate, rsum, racc, acc, prevm, &L);
  }

  #pragma unroll
  for (int j = 0; j < 8; ++j){
    size_t o = base + (size_t)j * 512;
    dout[o]           = v[j];
    dout[262144 + o]  = isy[j];
    dout[524288 + o]  = rate[j];
    dout[786432 + o]  = ((prevm >> j) & 1u) ? 1.0f : 0.0f;
    rmean[o] = rsum[j] * 0.00390625f;
  }
}

// ---------------- output head: R_out * rate_mean @ (kernel_out & exc_mask) ----------------
__global__ __launch_bounds__(256) void out_gemm(const float* __restrict__ rmean,
                                                const int* __restrict__ ko,
                                                const u32* __restrict__ flag,
                                                float* __restrict__ dout){
  const int b = blockIdx.x;
  const int o = blockIdx.y * 256 + threadIdx.x;
  const bool bm = (*flag) != 0;
  const unsigned char* kob = (const unsigned char*)ko;
  const float* rm = rmean + (size_t)b * 4096;
  float s = 0.f;
  #pragma unroll 8
  for (int n = 0; n < 2048; ++n){
    size_t idx = (size_t)n * 512 + o;
    int kv = bm ? (int)kob[idx] : ko[idx];
    s += rm[n] * (float)kv;
  }
  dout[1048576 + (size_t)b * 512 + o] = R_OUT * s;
}

extern "C" void kernel_launch(void* const* d_in, const int* in_sizes, int n_in,
                              void* d_out, int out_size, void* d_ws, size_t ws_size,
                              hipStream_t stream){
  (void)in_sizes; (void)n_in; (void)out_size; (void)ws_size;
  const float* x   = (const float*)d_in[0];
  const float* v0  = (const float*)d_in[1];
  const float* is0 = (const float*)d_in[2];
  const float* r0  = (const float*)d_in[3];
  const int*   s0  = (const int*)d_in[4];
  const int*   kin = (const int*)d_in[5];
  const int*   kh  = (const int*)d_in[6];
  const int*   ko  = (const int*)d_in[7];
  float* out = (float*)d_out;
  char* ws = (char*)d_ws;

  // rmean overlaps xb: xb is dead after gemm_iin, rmean written by snn_scan afterwards.
  u16*  xb    = (u16*)(ws);                       // [0, 33554432)
  float* rmean= (float*)(ws);                     // [0, 1048576)  lifetime-disjoint with xb
  float* sbeta= (float*)(ws + 33554432);          // 65,536 B
  u16*  iin   = (u16*)(ws + 33619968);            // 134,217,728 B
  u16*  Bt    = (u16*)(ws + 167837696);           // 8,388,608 B
  u64*  khT   = (u64*)(ws + 176226304);           // 2,097,152 B
  unsigned char* khB = (unsigned char*)(ws + 178323456);  // 2,097,152 B
  u32*  flag  = (u32*)(ws + 180420608);           // 4 B

  hipMemsetAsync(flag, 0, 4, stream);
  detect_layout<<<dim3(1), dim3(256), 0, stream>>>((const u32*)kh, flag);
  prep_x<<<dim3(16384), dim3(256), 0, stream>>>(x, xb, sbeta);
  prep_bt<<<dim3(16, 64), dim3(256), 0, stream>>>(kin, flag, Bt);
  prep_kh<<<dim3(16, 64), dim3(256), 0, stream>>>(kh, flag, khT);
  prep_khB<<<dim3(4096), dim3(256), 0, stream>>>(kh, flag, khB);
  gemm_iin<<<dim3(128, 32), dim3(256), 0, stream>>>(xb, Bt, sbeta, iin);
  snn_scan<<<dim3(64), dim3(512), 0, stream>>>(iin, khT, khB, v0, is0, r0, s0, out, rmean);
  out_gemm<<<dim3(64, 2), dim3(256), 0, stream>>>(rmean, ko, flag, out);
}

// Round 8
// 1531.425 us; speedup vs baseline: 1.0404x; 1.0214x over previous
//
#include <hip/hip_runtime.h>

typedef unsigned short u16;
typedef unsigned int   u32;
typedef unsigned long long u64;

typedef short bf16x8 __attribute__((ext_vector_type(8)));
typedef float f32x4  __attribute__((ext_vector_type(4)));
typedef unsigned short ushort8 __attribute__((ext_vector_type(8)));

#define A_SYN  0.90483741803595957f   // exp(-0.5/5)
#define A_VM   0.95122942450071400f   // exp(-0.5/10)
#define BETA   0.04877057549928600f   // 1 - A_VM
#define C_RATE 0.09754115099857200f   // (1/DT)*(1-alpha_out) = 2*BETA
#define R_H    0.04419417382415922f   // 1*1*10/5 * sqrt(1/2048)
#define R_IN   4.41941738241592200f   // 10*1*10 * sqrt(1/512)
#define R_OUT  2.20970869120796080f   // 100 * sqrt(1/2048)

__device__ __forceinline__ u16 f2b(float f){
  u32 x = __float_as_uint(f);
  return (u16)((x + 0x7FFFu + ((x >> 16) & 1u)) >> 16);   // RNE f32->bf16
}
__device__ __forceinline__ float b2f(u16 u){ return __uint_as_float(((u32)u) << 16); }

// ---------------- prep: row sums of x -> sbeta[m]; convert x to bf16 ----------------
__global__ __launch_bounds__(256) void prep_x(const float* __restrict__ x,
                                              u16* __restrict__ xb,
                                              float* __restrict__ sbeta){
  const int m = blockIdx.x;
  const int tid = threadIdx.x;
  const float4 xv = ((const float4*)(x + (size_t)m * 1024))[tid];
  float s = xv.x + xv.y + xv.z + xv.w;
  #pragma unroll
  for (int off = 32; off > 0; off >>= 1) s += __shfl_down(s, off, 64);
  __shared__ float ps[4];
  if ((tid & 63) == 0) ps[tid >> 6] = s;
  __syncthreads();
  float tot = ps[0] + ps[1] + ps[2] + ps[3];
  float sc = fminf(30.0f / (tot + 1.0f), 10.0f) * (R_IN * BETA);
  if (tid == 0) sbeta[m] = sc;
  ushort4 o; o.x = f2b(xv.x); o.y = f2b(xv.y); o.z = f2b(xv.z); o.w = f2b(xv.w);
  ((ushort4*)(xb + (size_t)m * 1024))[tid] = o;
}

// ---------------- detect bool layout: int32 words (0/1) vs packed bytes ----------------
__global__ void detect_layout(const u32* __restrict__ khw, u32* __restrict__ flag){
  u32 bad = 0;
  #pragma unroll
  for (int i = 0; i < 4; ++i){ u32 v = khw[threadIdx.x + i * 256]; bad |= (v > 1u) ? 1u : 0u; }
  if (bad) *flag = 1u;
}

// ---------------- prep: kernel_in -> Bt[n][k] bf16 (transposed) ----------------
__global__ __launch_bounds__(256) void prep_bt(const int* __restrict__ ki,
                                               const u32* __restrict__ flag,
                                               u16* __restrict__ Bt){
  __shared__ u16 tile[64][65];
  const int k0 = blockIdx.x * 64, n0 = blockIdx.y * 64;
  const int tr = threadIdx.x >> 6, tc = threadIdx.x & 63;
  const bool bm = (*flag) != 0;
  const unsigned char* kib = (const unsigned char*)ki;
  #pragma unroll 4
  for (int r = 0; r < 16; ++r){
    int row = r * 4 + tr;
    size_t idx = (size_t)(k0 + row) * 4096 + (n0 + tc);
    int v = bm ? (int)kib[idx] : ki[idx];
    tile[row][tc] = v ? (u16)0x3F80 : (u16)0;
  }
  __syncthreads();
  #pragma unroll 4
  for (int r = 0; r < 16; ++r){
    int row = r * 4 + tr;
    Bt[(size_t)(n0 + row) * 1024 + (k0 + tc)] = tile[tc][row];
  }
}

// -------- prep: kernel_h -> khT2 [w2=ww*8+j][n], bit l = kh[512*ww+8*l+j][n] --------
__global__ __launch_bounds__(256) void prep_kh2(const int* __restrict__ kh,
                                                const u32* __restrict__ flag,
                                                u64* __restrict__ khT2){
  const int n = blockIdx.x * 256 + threadIdx.x;
  const int w2 = blockIdx.y;
  const int ww = w2 >> 3, j = w2 & 7;
  const bool bm = (*flag) != 0;
  const unsigned char* khb = (const unsigned char*)kh;
  u64 bits = 0;
  #pragma unroll 8
  for (int l = 0; l < 64; ++l){
    int p = 512 * ww + 8 * l + j;
    size_t idx = (size_t)p * 4096 + n;
    int v = bm ? (int)khb[idx] : kh[idx];
    bits |= (u64)(v & 1) << l;
  }
  khT2[(size_t)w2 * 4096 + n] = bits;
}

// -------- prep: kernel_h -> khB2[p][c], bit jj = kh[p][8*c+jj] --------
__global__ __launch_bounds__(256) void prep_khB2(const int* __restrict__ kh,
                                                 const u32* __restrict__ flag,
                                                 unsigned char* __restrict__ khB){
  const int p = blockIdx.x;
  const bool bm = (*flag) != 0;
  #pragma unroll
  for (int half = 0; half < 2; ++half){
    const int c = threadIdx.x + half * 256;
    u32 b = 0;
    if (bm){
      const unsigned char* r = (const unsigned char*)kh + (size_t)p * 4096 + 8 * c;
      #pragma unroll
      for (int j = 0; j < 8; ++j) b |= (u32)(r[j] & 1) << j;
    } else {
      const int* r = kh + (size_t)p * 4096 + 8 * c;
      #pragma unroll
      for (int j = 0; j < 8; ++j) b |= (u32)(r[j] & 1) << j;
    }
    khB[((size_t)p << 9) + c] = (unsigned char)b;
  }
}

// ---------------- bf16 GEMM with XCD swizzle ----------------
__global__ __launch_bounds__(256) void gemm_iin(const u16* __restrict__ A,
                                                const u16* __restrict__ Bm,
                                                const float* __restrict__ sbeta,
                                                u16* __restrict__ C){
  __shared__ u16 As[128 * 32];
  __shared__ u16 Bs[128 * 32];
  const int tid = threadIdx.x;
  const int lane = tid & 63, w = tid >> 6;
  const int wm = w >> 1, wn = w & 1;
  const int id = blockIdx.y * 128 + blockIdx.x;
  const int swz = (id & 7) * 512 + (id >> 3);
  const int m0 = (swz & 127) * 128, n0 = (swz >> 7) * 128;
  const int l15 = lane & 15, lq = lane >> 4;
  const int K = 1024;

  f32x4 acc[4][4];
  #pragma unroll
  for (int i = 0; i < 4; ++i)
    #pragma unroll
    for (int j = 0; j < 4; ++j) acc[i][j] = (f32x4){0.f, 0.f, 0.f, 0.f};

  const u16* ag = A  + (size_t)(m0 + (tid >> 2)) * K + (tid & 3) * 8;
  const u16* bg = Bm + (size_t)(n0 + (tid >> 2)) * K + (tid & 3) * 8;

  for (int kt = 0; kt < 32; ++kt){
    __builtin_amdgcn_global_load_lds((const __attribute__((address_space(1))) u32*)(ag + kt * 32),
        (__attribute__((address_space(3))) u32*)(As + tid * 8), 16, 0, 0);
    __builtin_amdgcn_global_load_lds((const __attribute__((address_space(1))) u32*)(ag + (size_t)64 * K + kt * 32),
        (__attribute__((address_space(3))) u32*)(As + 2048 + tid * 8), 16, 0, 0);
    __builtin_amdgcn_global_load_lds((const __attribute__((address_space(1))) u32*)(bg + kt * 32),
        (__attribute__((address_space(3))) u32*)(Bs + tid * 8), 16, 0, 0);
    __builtin_amdgcn_global_load_lds((const __attribute__((address_space(1))) u32*)(bg + (size_t)64 * K + kt * 32),
        (__attribute__((address_space(3))) u32*)(Bs + 2048 + tid * 8), 16, 0, 0);
    __syncthreads();
    bf16x8 af[4], bf[4];
    #pragma unroll
    for (int f = 0; f < 4; ++f){
      af[f] = *(const bf16x8*)(As + (wm * 64 + f * 16 + l15) * 32 + lq * 8);
      bf[f] = *(const bf16x8*)(Bs + (wn * 64 + f * 16 + l15) * 32 + lq * 8);
    }
    #pragma unroll
    for (int fm = 0; fm < 4; ++fm)
      #pragma unroll
      for (int fn = 0; fn < 4; ++fn)
        acc[fm][fn] = __builtin_amdgcn_mfma_f32_16x16x32_bf16(af[fm], bf[fn], acc[fm][fn], 0, 0, 0);
    __syncthreads();
  }

  float sb[4][4];
  #pragma unroll
  for (int fm = 0; fm < 4; ++fm)
    #pragma unroll
    for (int i = 0; i < 4; ++i)
      sb[fm][i] = sbeta[m0 + wm * 64 + fm * 16 + lq * 4 + i];
  #pragma unroll
  for (int fm = 0; fm < 4; ++fm)
    #pragma unroll
    for (int fn = 0; fn < 4; ++fn)
      #pragma unroll
      for (int i = 0; i < 4; ++i){
        size_t row = (size_t)(m0 + wm * 64 + fm * 16 + lq * 4 + i);
        int col = n0 + wn * 64 + fn * 16 + l15;
        C[row * 4096 + col] = f2b(acc[fm][fn][i] * sb[fm][i]);
      }
}

// ======== SNN scan: 512 threads, neurons n = 8*tid + j, raw-barrier (no vmcnt drain) ========
// event u32: bits0-11 p | bit12 neg.  exc presyn <=> wave ww<4 (p = 8*(ww*64+lane)+j < 2048).

struct ScanLds {
  unsigned char cntb[2][8];                      // per-wave flip count (0xFF = dense)
  u32 seg[2][8][4] __attribute__((aligned(16)));
  u64 fpos[2][64], fneg[2][64];                  // [ww*8+j], dense path only
};

__device__ __forceinline__ void produce(
    int lane, int ww, int buf,
    const u64 (&bsp)[8], const u64 (&bfl)[8], bool wany, ScanLds* L)
{
  if (lane == 0){
    u32 cb = 0;
    if (wany){
      int cnt = 0;
      #pragma unroll
      for (int j = 0; j < 8; ++j) cnt += __popcll(bfl[j]);
      if (cnt <= 4){
        cb = (u32)cnt;
        int idx = 0;
        #pragma unroll 1
        for (int j = 0; j < 8; ++j){
          u64 m = bfl[j];
          while (m){
            int bit = (int)__builtin_ctzll(m); m &= m - 1;
            u32 p = (u32)(((ww << 6) + bit) * 8 + j);
            u32 rising = (u32)((bsp[j] >> bit) & 1ull);
            u32 neg = (ww < 4) ? (rising ^ 1u) : rising;   // dale sign, wave-uniform class
            L->seg[buf][ww][idx++] = p | (neg << 12);
          }
        }
      } else {
        cb = 0xFFu;
        #pragma unroll
        for (int j = 0; j < 8; ++j){
          L->fpos[buf][ww * 8 + j] = bfl[j] & bsp[j];
          L->fneg[buf][ww * 8 + j] = bfl[j] & ~bsp[j];
        }
      }
    }
    L->cntb[buf][ww] = (unsigned char)cb;
  }
}

__device__ __forceinline__ void consume(
    int tid, int buf,
    const u64* __restrict__ khT2, const unsigned char* __restrict__ khB,
    ScanLds* L, int (&acc)[8], float (&racc)[8])
{
  const u64 cw = *(const u64*)&L->cntb[buf][0];
  if (cw == 0ull) return;

  u32 evs[8][4], byv[8][4];
  // phase 1: read segs, issue ALL khB byte loads (independent -> one latency)
  #pragma unroll
  for (int ww = 0; ww < 8; ++ww){
    u32 c = (u32)((cw >> (8 * ww)) & 0xFFull);
    if (c == 0u || c == 0xFFu) continue;          // wave-uniform branch
    uint4 q = *(const uint4*)&L->seg[buf][ww][0];
    evs[ww][0] = q.x; evs[ww][1] = q.y; evs[ww][2] = q.z; evs[ww][3] = q.w;
    #pragma unroll
    for (int k = 0; k < 4; ++k)
      if ((u32)k < c)
        byv[ww][k] = khB[((size_t)(evs[ww][k] & 4095u) << 9) + tid];
  }
  // phase 2: dense waves (t=0 onset / rare bursts): khT2 popcount, contiguous 64B/thread
  if (cw & 0x8080808080808080ull){
    #pragma unroll 1
    for (int ww = 0; ww < 8; ++ww){
      if (((cw >> (8 * ww)) & 0xFFull) != 0xFFull) continue;
      #pragma unroll 1
      for (int j = 0; j < 8; ++j){
        int w2 = ww * 8 + j;
        u64 fpm = L->fpos[buf][w2], fnm = L->fneg[buf][w2];
        if (!(fpm | fnm)) continue;
        const u64* kp = khT2 + ((size_t)w2 << 12) + 8 * tid;
        #pragma unroll
        for (int jj = 0; jj < 8; ++jj){
          u64 k = kp[jj];
          int tt = __popcll(fpm & k) - __popcll(fnm & k);
          acc[jj] += (ww < 4) ? tt : -tt;
        }
      }
    }
  }
  // phase 3: apply sparse events (pure VALU)
  #pragma unroll
  for (int ww = 0; ww < 8; ++ww){
    u32 c = (u32)((cw >> (8 * ww)) & 0xFFull);
    if (c == 0u || c == 0xFFu) continue;
    #pragma unroll
    for (int k = 0; k < 4; ++k){
      if ((u32)k < c){
        u32 b = byv[ww][k];
        if (evs[ww][k] & (1u << 12)){
          #pragma unroll
          for (int j = 0; j < 8; ++j) acc[j] -= (int)((b >> j) & 1u);
        } else {
          #pragma unroll
          for (int j = 0; j < 8; ++j) acc[j] += (int)((b >> j) & 1u);
        }
      }
    }
  }
  #pragma unroll
  for (int j = 0; j < 8; ++j) racc[j] = R_H * (float)acc[j];
}

__device__ __forceinline__ void snn_step(
    int t, int tid, int lane, int ww, const u16* __restrict__ ip,
    const u64* __restrict__ khT2, const unsigned char* __restrict__ khB,
    ushort8 &cur,
    float (&v)[8], float (&isy)[8], float (&rate)[8], float (&rsum)[8],
    float (&racc)[8], int (&acc)[8], u32 &prevm,
    ScanLds* L)
{
  const int buf = t & 1;
  u32 snm = 0;
  #pragma unroll
  for (int j = 0; j < 8; ++j){
    isy[j] = fmaf(isy[j], A_SYN, racc[j]);
    float tv = fmaf(isy[j], BETA, b2f((u16)cur[j]));   // beta*i_syn + beta*R_in*scale*(x@Kin)
    float vv = fmaf(v[j], A_VM, tv);
    bool sj = vv > 1.0f;
    v[j] = sj ? 0.0f : vv;
    rate[j] = fmaf(rate[j], A_VM, sj ? C_RATE : 0.0f);  // alpha_out == alpha_vm
    rsum[j] += rate[j];
    snm |= (u32)sj << j;
  }
  const u32 flm = snm ^ prevm;
  prevm = snm;
  const bool wany = __any(flm != 0);
  u64 bsp[8] = {0,0,0,0,0,0,0,0}, bfl[8] = {0,0,0,0,0,0,0,0};
  if (wany){
    #pragma unroll
    for (int j = 0; j < 8; ++j){
      bsp[j] = __ballot((int)((snm >> j) & 1u));
      bfl[j] = __ballot((int)((flm >> j) & 1u));
    }
  }
  produce(lane, ww, buf, bsp, bfl, wany, L);
  // raw barrier: LDS-order only, NO vmcnt drain (prefetch stays in flight across steps)
  __builtin_amdgcn_sched_barrier(0);
  asm volatile("s_waitcnt lgkmcnt(0)" ::: "memory");
  __builtin_amdgcn_sched_barrier(0);
  __builtin_amdgcn_s_barrier();
  __builtin_amdgcn_sched_barrier(0);
  // refill this slot for t+4 (4-deep pipeline, counted vmcnt at use)
  if (t + 4 < 256)
    cur = *(const ushort8*)(ip + (size_t)(t + 4) * 4096);
  consume(tid, buf, khT2, khB, L, acc, racc);
}

__global__ __launch_bounds__(512, 1) void snn_scan(
    const u16* __restrict__ iin, const u64* __restrict__ khT2,
    const unsigned char* __restrict__ khB,
    const float* __restrict__ v0, const float* __restrict__ is0,
    const float* __restrict__ r0, const int* __restrict__ s0,
    float* __restrict__ dout, float* __restrict__ rmean)
{
  const int b = blockIdx.x, tid = threadIdx.x;
  const int lane = tid & 63, ww = tid >> 6;    // 8 waves
  __shared__ ScanLds L;

  float v[8], isy[8], rate[8], rsum[8], racc[8];
  int acc[8]; u32 prevm = 0;
  const size_t base8 = (size_t)b * 4096 + 8 * tid;   // neuron n = 8*tid + j
  const unsigned char* s0b = (const unsigned char*)s0;  // spike0 all-zero; byte-safe either layout
  {
    float4 va = ((const float4*)(v0  + base8))[0], vb = ((const float4*)(v0  + base8))[1];
    float4 ia = ((const float4*)(is0 + base8))[0], ib = ((const float4*)(is0 + base8))[1];
    float4 ra = ((const float4*)(r0  + base8))[0], rb = ((const float4*)(r0  + base8))[1];
    v[0]=va.x; v[1]=va.y; v[2]=va.z; v[3]=va.w; v[4]=vb.x; v[5]=vb.y; v[6]=vb.z; v[7]=vb.w;
    isy[0]=ia.x; isy[1]=ia.y; isy[2]=ia.z; isy[3]=ia.w; isy[4]=ib.x; isy[5]=ib.y; isy[6]=ib.z; isy[7]=ib.w;
    rate[0]=ra.x; rate[1]=ra.y; rate[2]=ra.z; rate[3]=ra.w; rate[4]=rb.x; rate[5]=rb.y; rate[6]=rb.z; rate[7]=rb.w;
  }
  #pragma unroll
  for (int j = 0; j < 8; ++j){
    rsum[j] = 0.f;
    prevm |= (u32)(s0b[base8 + j] != 0) << j;
    acc[j] = 0; racc[j] = 0.f;
  }
  __syncthreads();   // one-time (LDS not yet used; orders nothing critical)

  { // init event (buf=1): flips = spike0 rising
    u64 bsp[8] = {0,0,0,0,0,0,0,0}, bfl[8] = {0,0,0,0,0,0,0,0};
    bool wany = __any(prevm != 0);
    if (wany){
      #pragma unroll
      for (int j = 0; j < 8; ++j){
        bsp[j] = __ballot((int)((prevm >> j) & 1u));
        bfl[j] = bsp[j];
      }
    }
    produce(lane, ww, 1, bsp, bfl, wany, &L);
    __syncthreads();
    consume(tid, 1, khT2, khB, &L, acc, racc);
  }

  const u16* ip = iin + (size_t)b * 256 * 4096 + 8 * tid;
  ushort8 bufA = *(const ushort8*)(ip);
  ushort8 bufB = *(const ushort8*)(ip + 4096);
  ushort8 bufC = *(const ushort8*)(ip + 8192);
  ushort8 bufD = *(const ushort8*)(ip + 12288);

  for (int t = 0; t < 256; t += 4){
    snn_step(t,     tid, lane, ww, ip, khT2, khB, bufA,
             v, isy, rate, rsum, racc, acc, prevm, &L);
    snn_step(t + 1, tid, lane, ww, ip, khT2, khB, bufB,
             v, isy, rate, rsum, racc, acc, prevm, &L);
    snn_step(t + 2, tid, lane, ww, ip, khT2, khB, bufC,
             v, isy, rate, rsum, racc, acc, prevm, &L);
    snn_step(t + 3, tid, lane, ww, ip, khT2, khB, bufD,
             v, isy, rate, rsum, racc, acc, prevm, &L);
  }

  #pragma unroll
  for (int j = 0; j < 8; ++j){
    size_t o = base8 + j;
    dout[o]           = v[j];
    dout[262144 + o]  = isy[j];
    dout[524288 + o]  = rate[j];
    dout[786432 + o]  = ((prevm >> j) & 1u) ? 1.0f : 0.0f;
    rmean[o] = rsum[j] * 0.00390625f;
  }
}

// ---------------- output head: R_out * rate_mean @ (kernel_out & exc_mask) ----------------
__global__ __launch_bounds__(256) void out_gemm(const float* __restrict__ rmean,
                                                const int* __restrict__ ko,
                                                const u32* __restrict__ flag,
                                                float* __restrict__ dout){
  const int b = blockIdx.x;
  const int o = blockIdx.y * 256 + threadIdx.x;
  const bool bm = (*flag) != 0;
  const unsigned char* kob = (const unsigned char*)ko;
  const float* rm = rmean + (size_t)b * 4096;
  float s = 0.f;
  #pragma unroll 8
  for (int n = 0; n < 2048; ++n){
    size_t idx = (size_t)n * 512 + o;
    int kv = bm ? (int)kob[idx] : ko[idx];
    s += rm[n] * (float)kv;
  }
  dout[1048576 + (size_t)b * 512 + o] = R_OUT * s;
}

extern "C" void kernel_launch(void* const* d_in, const int* in_sizes, int n_in,
                              void* d_out, int out_size, void* d_ws, size_t ws_size,
                              hipStream_t stream){
  (void)in_sizes; (void)n_in; (void)out_size; (void)ws_size;
  const float* x   = (const float*)d_in[0];
  const float* v0  = (const float*)d_in[1];
  const float* is0 = (const float*)d_in[2];
  const float* r0  = (const float*)d_in[3];
  const int*   s0  = (const int*)d_in[4];
  const int*   kin = (const int*)d_in[5];
  const int*   kh  = (const int*)d_in[6];
  const int*   ko  = (const int*)d_in[7];
  float* out = (float*)d_out;
  char* ws = (char*)d_ws;

  // rmean overlaps xb: xb is dead after gemm_iin, rmean written by snn_scan afterwards.
  u16*  xb    = (u16*)(ws);                       // [0, 33554432)
  float* rmean= (float*)(ws);                     // [0, 1048576)  lifetime-disjoint with xb
  float* sbeta= (float*)(ws + 33554432);          // 65,536 B
  u16*  iin   = (u16*)(ws + 33619968);            // 134,217,728 B
  u16*  Bt    = (u16*)(ws + 167837696);           // 8,388,608 B
  u64*  khT2  = (u64*)(ws + 176226304);           // 2,097,152 B
  unsigned char* khB = (unsigned char*)(ws + 178323456);  // 2,097,152 B
  u32*  flag  = (u32*)(ws + 180420608);           // 4 B

  hipMemsetAsync(flag, 0, 4, stream);
  detect_layout<<<dim3(1), dim3(256), 0, stream>>>((const u32*)kh, flag);
  prep_x<<<dim3(16384), dim3(256), 0, stream>>>(x, xb, sbeta);
  prep_bt<<<dim3(16, 64), dim3(256), 0, stream>>>(kin, flag, Bt);
  prep_kh2<<<dim3(16, 64), dim3(256), 0, stream>>>(kh, flag, khT2);
  prep_khB2<<<dim3(4096), dim3(256), 0, stream>>>(kh, flag, khB);
  gemm_iin<<<dim3(128, 32), dim3(256), 0, stream>>>(xb, Bt, sbeta, iin);
  snn_scan<<<dim3(64), dim3(512), 0, stream>>>(iin, khT2, khB, v0, is0, r0, s0, out, rmean);
  out_gemm<<<dim3(64, 2), dim3(256), 0, stream>>>(rmean, ko, flag, out);
}